// Round 1
// baseline (672.613 us; speedup 1.0000x reference)
//
#include <hip/hip_runtime.h>
#include <hip/hip_bf16.h>

// Segment-mean over contiguous ragged batches.
//   x:            [N, D] float32   (N = sum(batch_lengths), D = 128 here)
//   batch_lengths:[B]    int32
//   out:          [B, D] float32   (per-segment column means)
//
// Kernel 1: exclusive prefix scan of batch_lengths -> segment offsets (d_ws).
// Kernel 2: one 512-thread block per segment; float4-coalesced accumulate,
//           LDS tree reduce over 16 row-groups, scale by 1/len, store.

__global__ void seg_scan_kernel(const int* __restrict__ lens,
                                int* __restrict__ offs, int B) {
    __shared__ int buf[1024];
    __shared__ int carry_s;
    const int t = threadIdx.x;
    if (t == 0) carry_s = 0;
    __syncthreads();
    for (int base = 0; base < B; base += 1024) {
        const int idx = base + t;
        const int v = (idx < B) ? lens[idx] : 0;
        buf[t] = v;
        __syncthreads();
        // Hillis-Steele inclusive scan in LDS
        for (int s = 1; s < 1024; s <<= 1) {
            int add = (t >= s) ? buf[t - s] : 0;
            __syncthreads();
            buf[t] += add;
            __syncthreads();
        }
        if (idx < B) offs[idx] = carry_s + buf[t] - v;  // exclusive
        __syncthreads();
        if (t == 0) carry_s += buf[1023];
        __syncthreads();
    }
}

// D is hard-wired to 128 floats = 32 float4 per row.
__global__ __launch_bounds__(512)
void seg_mean_kernel(const float* __restrict__ x,
                     const int* __restrict__ lens,
                     const int* __restrict__ offs,
                     float* __restrict__ out) {
    const int b    = blockIdx.x;
    const int t    = threadIdx.x;
    const int lane = t & 31;   // column quad: cols [lane*4, lane*4+3]
    const int rowg = t >> 5;   // row group 0..15

    const int L = lens[b];
    const int O = offs[b];

    // 32 float4 per row; wave (64 lanes) covers 2 full rows -> 1 KiB coalesced
    const float4* __restrict__ xp =
        reinterpret_cast<const float4*>(x) + (size_t)O * 32 + lane;

    float4 acc = make_float4(0.f, 0.f, 0.f, 0.f);
    #pragma unroll 4
    for (int r = rowg; r < L; r += 16) {
        const float4 v = xp[(size_t)r * 32];
        acc.x += v.x; acc.y += v.y; acc.z += v.z; acc.w += v.w;
    }

    __shared__ float4 red[512];
    red[t] = acc;
    __syncthreads();
    // reduce over row-group dimension (16 groups of 32 lanes)
    #pragma unroll
    for (int s = 256; s >= 32; s >>= 1) {
        if (t < s) {
            float4 a = red[t];
            const float4 c = red[t + s];
            a.x += c.x; a.y += c.y; a.z += c.z; a.w += c.w;
            red[t] = a;
        }
        __syncthreads();
    }
    if (t < 32) {
        const float inv = 1.0f / (float)L;
        float4 a = red[t];
        a.x *= inv; a.y *= inv; a.z *= inv; a.w *= inv;
        reinterpret_cast<float4*>(out)[(size_t)b * 32 + t] = a;
    }
}

// Generic (slow) fallback for unexpected shapes: one thread per output elem.
__global__ void seg_mean_generic_kernel(const float* __restrict__ x,
                                        const int* __restrict__ lens,
                                        const int* __restrict__ offs,
                                        float* __restrict__ out,
                                        int B, int D) {
    const int i = blockIdx.x * blockDim.x + threadIdx.x;
    if (i >= B * D) return;
    const int b = i / D, d = i - b * D;
    const int L = lens[b], O = offs[b];
    float s = 0.f;
    for (int r = 0; r < L; ++r) s += x[(size_t)(O + r) * D + d];
    out[i] = s / (float)L;
}

extern "C" void kernel_launch(void* const* d_in, const int* in_sizes, int n_in,
                              void* d_out, int out_size, void* d_ws, size_t ws_size,
                              hipStream_t stream) {
    const float* x    = (const float*)d_in[0];
    const int*   lens = (const int*)d_in[1];
    float*       out  = (float*)d_out;
    const int B = in_sizes[1];
    const int D = out_size / B;

    int* offs = (int*)d_ws;  // B ints of scratch

    seg_scan_kernel<<<1, 1024, 0, stream>>>(lens, offs, B);

    if (D == 128) {
        seg_mean_kernel<<<B, 512, 0, stream>>>(x, lens, offs, out);
    } else {
        const int total = B * D;
        seg_mean_generic_kernel<<<(total + 255) / 256, 256, 0, stream>>>(
            x, lens, offs, out, B, D);
    }
}

// Round 3
// 638.786 us; speedup vs baseline: 1.0530x; 1.0530x over previous
//
#include <hip/hip_runtime.h>
#include <hip/hip_bf16.h>

// Segment-mean over contiguous ragged batches, single fused kernel.
//   x:            [N, D] float32   (D = 128 fast path)
//   batch_lengths:[B]    int32
//   out:          [B, D] float32
//
// One 512-thread block per segment. Each block:
//   1. computes its own exclusive offset O = sum(lens[0..b)) via a
//      coalesced block reduction over the (L2-resident, 4 KB) lens array,
//   2. accumulates its rows with nontemporal float4 loads (16 row-groups
//      x 32 column-quads, 1 KiB contiguous per wave-iteration),
//   3. LDS tree-reduces over row-groups, scales by 1/L, stores.

#define TPB 512

// Native vector type for __builtin_nontemporal_load (HIP_vector_type invalid).
typedef float floatx4 __attribute__((ext_vector_type(4)));

__device__ __forceinline__ int block_excl_offset(const int* __restrict__ lens,
                                                 int b, int t) {
    __shared__ int s_wave[TPB / 64];
    __shared__ int s_O;
    int partial = 0;
    for (int i = t; i < b; i += TPB) partial += lens[i];
    #pragma unroll
    for (int d = 32; d >= 1; d >>= 1) partial += __shfl_down(partial, d, 64);
    if ((t & 63) == 0) s_wave[t >> 6] = partial;
    __syncthreads();
    if (t == 0) {
        int o = 0;
        #pragma unroll
        for (int w = 0; w < TPB / 64; ++w) o += s_wave[w];
        s_O = o;
    }
    __syncthreads();
    return s_O;
}

// Fast path: D == 128 floats (32 float4 per row).
__global__ __launch_bounds__(TPB)
void seg_mean128_kernel(const float* __restrict__ x,
                        const int* __restrict__ lens,
                        float* __restrict__ out) {
    const int b    = blockIdx.x;
    const int t    = threadIdx.x;
    const int lane = t & 31;   // column quad
    const int rowg = t >> 5;   // row group 0..15

    const int O = block_excl_offset(lens, b, t);
    const int L = lens[b];

    const floatx4* __restrict__ xp =
        reinterpret_cast<const floatx4*>(x) + (size_t)O * 32 + lane;

    floatx4 acc = (floatx4)(0.f);
    #pragma unroll 8
    for (int r = rowg; r < L; r += 16) {
        const floatx4 v = __builtin_nontemporal_load(&xp[(size_t)r * 32]);
        acc += v;
    }

    __shared__ floatx4 red[TPB];
    red[t] = acc;
    __syncthreads();
    #pragma unroll
    for (int s = TPB / 2; s >= 32; s >>= 1) {
        if (t < s) {
            red[t] += red[t + s];
        }
        __syncthreads();
    }
    if (t < 32) {
        const float inv = (L > 0) ? 1.0f / (float)L : 0.0f;
        floatx4 a = red[t] * inv;
        reinterpret_cast<floatx4*>(out)[(size_t)b * 32 + t] = a;
    }
}

// Generic fallback: arbitrary D, scalar loads, one block per segment.
__global__ __launch_bounds__(TPB)
void seg_mean_generic_kernel(const float* __restrict__ x,
                             const int* __restrict__ lens,
                             float* __restrict__ out, int D) {
    const int b = blockIdx.x;
    const int t = threadIdx.x;

    const int O = block_excl_offset(lens, b, t);
    const int L = lens[b];
    const float inv = (L > 0) ? 1.0f / (float)L : 0.0f;

    for (int d = t; d < D; d += TPB) {
        float s = 0.f;
        for (int r = 0; r < L; ++r) s += x[(size_t)(O + r) * D + d];
        out[(size_t)b * D + d] = s * inv;
    }
}

extern "C" void kernel_launch(void* const* d_in, const int* in_sizes, int n_in,
                              void* d_out, int out_size, void* d_ws, size_t ws_size,
                              hipStream_t stream) {
    const float* x    = (const float*)d_in[0];
    const int*   lens = (const int*)d_in[1];
    float*       out  = (float*)d_out;
    const int B = in_sizes[1];
    const int D = out_size / B;

    if (D == 128) {
        seg_mean128_kernel<<<B, TPB, 0, stream>>>(x, lens, out);
    } else {
        seg_mean_generic_kernel<<<B, TPB, 0, stream>>>(x, lens, out, D);
    }
}